// Round 4
// baseline (104.341 us; speedup 1.0000x reference)
//
#include <hip/hip_runtime.h>

typedef __attribute__((ext_vector_type(8))) short bf16x8;
typedef __attribute__((ext_vector_type(4))) float f32x4;
typedef __attribute__((ext_vector_type(2))) unsigned int u32x2;
typedef __attribute__((ext_vector_type(4))) unsigned int u32x4;

__device__ __forceinline__ unsigned short f2bf(float f) {
  return __builtin_bit_cast(unsigned short, (__bf16)f);
}
__device__ __forceinline__ unsigned pk2(float a, float b) {
  return (unsigned)f2bf(a) | ((unsigned)f2bf(b) << 16);
}
__device__ __forceinline__ float bf2f(unsigned short h) {
  unsigned u = ((unsigned)h) << 16;
  return __builtin_bit_cast(float, u);
}

// wave-level compiler memory fence: cross-lane LDS handoff within a wave has
// per-thread-disjoint addresses -> SIMT alias analysis may reorder write/read.
// Zero executed instructions; forbids compiler motion of memory ops across.
__device__ __forceinline__ void wfence() {
  asm volatile("" ::: "memory");
  __builtin_amdgcn_wave_barrier();
}

#define MFMA16(a, b, c) __builtin_amdgcn_mfma_f32_16x16x32_bf16(a, b, c, 0, 0, 0)

#define LR 72    // 64-col rows: 144 B stride (16B-aligned, bank-rotating)
// regions (ushort offsets):
//  H: LN1 out -> P(exp scores) -> attn scratch -> H2 scratch -> FF1 chunk scratch
//  Q, K: q/k row-major [token][dim];  VT: V transposed [dim][token]
#define OFF_H   0
#define OFF_Q   4608
#define OFF_K   9216
#define OFF_VT  13824
#define ZO      (OFF_Q + 64)   // 16B zero block in Q row-0 padding (cols 64..71)
#define LDS_TOT 18432          // 36,864 B -> 4 blocks/CU

// ---- weight prep: chunk c (1 KB) holds frag[l*8+jj] = W[k][n],
//      k = 32*ks + 8*(l>>4) + jj,  n = 16*T + (l&15).
// Used as A-frag of W^T (A[m=n][k]) everywhere (A-frag of W^T == B-frag of W).
// chunks: [0,8)=WqT(x 0.125*log2e) [8,16)=WkT [16,24)=WvT [24,32)=WpT
//         [32,64)=W1T (T=hidden tile 0..15, ks=cin 0..1)
//         [64,96)=W2T (T=cout tile 0..3,  ks=hidden 0..7)
__global__ void prep_weights(const float* __restrict__ wq, const float* __restrict__ wk,
                             const float* __restrict__ wv, const float* __restrict__ projw,
                             const float* __restrict__ fc1w, const float* __restrict__ fc2w,
                             unsigned short* __restrict__ ws) {
  int c = blockIdx.x, l = threadIdx.x;
  int g = l >> 4, jl = l & 15;
  int kind, T, ks;
  if (c < 8)       { kind = 0; T = c >> 1;        ks = c & 1; }
  else if (c < 16) { kind = 1; T = (c - 8) >> 1;  ks = (c - 8) & 1; }
  else if (c < 24) { kind = 2; T = (c - 16) >> 1; ks = (c - 16) & 1; }
  else if (c < 32) { kind = 3; T = (c - 24) >> 1; ks = (c - 24) & 1; }
  else if (c < 64) { kind = 4; T = (c - 32) >> 1; ks = (c - 32) & 1; }
  else             { kind = 5; T = (c - 64) >> 3; ks = (c - 64) & 7; }
  int n = 16 * T + jl;
  unsigned short* dst = ws + c * 512 + l * 8;
  #pragma unroll
  for (int jj = 0; jj < 8; ++jj) {
    int k = 32 * ks + 8 * g + jj;
    float v;
    if (kind == 0)      v = wq[(n >> 3) * 512 + k * 8 + (n & 7)] * (0.125f * 1.44269504f);
    else if (kind == 1) v = wk[(n >> 3) * 512 + k * 8 + (n & 7)];
    else if (kind == 2) v = wv[(n >> 3) * 512 + k * 8 + (n & 7)];
    else if (kind == 3) v = projw[k * 64 + n];
    else if (kind == 4) v = fc1w[k * 256 + n];
    else                v = fc2w[k * 64 + n];
    dst[jj] = f2bf(v);
  }
}

__global__ __launch_bounds__(256, 4) void block_fused(
    const float* __restrict__ x,
    const float* __restrict__ ln1w, const float* __restrict__ ln1b,
    const float* __restrict__ projb,
    const float* __restrict__ ln2w, const float* __restrict__ ln2b,
    const float* __restrict__ fc1b, const float* __restrict__ fc2b,
    const unsigned short* __restrict__ wsm, float* __restrict__ out) {
  __shared__ __attribute__((aligned(16))) unsigned short lds[LDS_TOT];

  const int tid  = threadIdx.x;
  const int w    = tid >> 6;     // wave 0..3 owns token rows 16w..16w+15
  const int lane = tid & 63;
  const int g    = lane >> 4;
  const int jl   = lane & 15;
  const size_t b = blockIdx.x;
  const float* xb = x + b * 4096;
  const f32x4 zf = {0.f, 0.f, 0.f, 0.f};

  const int myrow = 16 * w + jl;          // this lane's token
  const int prow  = OFF_H + myrow * LR;   // own scratch row (P/attn/H2/FF1)
  const int qrow  = OFF_Q + myrow * LR;
  const int krow  = OFF_K + myrow * LR;

  // ---------- LN1 (4 lanes/row; rows 16w..16w+15 are wave-private) ----------
  {
    int row = tid >> 2, q = tid & 3;
    const f32x4* xr = (const f32x4*)(xb + row * 64 + q * 16);
    f32x4 v0 = xr[0], v1 = xr[1], v2 = xr[2], v3 = xr[3];
    float s = 0.f, ss = 0.f;
    #pragma unroll
    for (int i = 0; i < 4; ++i) { s += v0[i] + v1[i] + v2[i] + v3[i];
      ss += v0[i]*v0[i] + v1[i]*v1[i] + v2[i]*v2[i] + v3[i]*v3[i]; }
    s  += __shfl_xor(s, 1, 64);  s  += __shfl_xor(s, 2, 64);
    ss += __shfl_xor(ss, 1, 64); ss += __shfl_xor(ss, 2, 64);
    float mean = s * 0.015625f;
    float rstd = rsqrtf(ss * 0.015625f - mean * mean + 1e-5f);
    const f32x4* wv4 = (const f32x4*)(ln1w + q * 16);
    const f32x4* bv4 = (const f32x4*)(ln1b + q * 16);
    f32x4 w0 = wv4[0], w1 = wv4[1], w2 = wv4[2], w3 = wv4[3];
    f32x4 b0 = bv4[0], b1 = bv4[1], b2 = bv4[2], b3 = bv4[3];
    f32x4 o0, o1, o2, o3;
    #pragma unroll
    for (int i = 0; i < 4; ++i) {
      o0[i] = (v0[i] - mean) * rstd * w0[i] + b0[i];
      o1[i] = (v1[i] - mean) * rstd * w1[i] + b1[i];
      o2[i] = (v2[i] - mean) * rstd * w2[i] + b2[i];
      o3[i] = (v3[i] - mean) * rstd * w3[i] + b3[i];
    }
    u32x4 lo = {pk2(o0[0],o0[1]), pk2(o0[2],o0[3]), pk2(o1[0],o1[1]), pk2(o1[2],o1[3])};
    u32x4 hi = {pk2(o2[0],o2[1]), pk2(o2[2],o2[3]), pk2(o3[0],o3[1]), pk2(o3[2],o3[3])};
    *(u32x4*)(lds + OFF_H + row * LR + q * 16)     = lo;
    *(u32x4*)(lds + OFF_H + row * LR + q * 16 + 8) = hi;
  }
  wfence();   // LN1 stores -> cross-lane H-row reads

  // ---------- QKV (swapped): D = W^T . H^T ; B-frag = own H row ----------
  {
    bf16x8 hb0 = *(const bf16x8*)(lds + prow + 8 * g);
    bf16x8 hb1 = *(const bf16x8*)(lds + prow + 32 + 8 * g);
    #pragma unroll
    for (int t = 0; t < 3; ++t) {
      #pragma unroll
      for (int mt = 0; mt < 4; ++mt) {
        bf16x8 a0 = *(const bf16x8*)(wsm + (t * 8 + mt * 2 + 0) * 512 + lane * 8);
        bf16x8 a1 = *(const bf16x8*)(wsm + (t * 8 + mt * 2 + 1) * 512 + lane * 8);
        f32x4 acc = MFMA16(a0, hb0, zf);
        acc = MFMA16(a1, hb1, acc);
        if (t == 0) {
          *(u32x2*)(lds + qrow + 16 * mt + 4 * g) = (u32x2){pk2(acc[0],acc[1]), pk2(acc[2],acc[3])};
        } else if (t == 1) {
          *(u32x2*)(lds + krow + 16 * mt + 4 * g) = (u32x2){pk2(acc[0],acc[1]), pk2(acc[2],acc[3])};
        } else {
          #pragma unroll
          for (int r = 0; r < 4; ++r)
            lds[OFF_VT + (16 * mt + 4 * g + r) * LR + myrow] = f2bf(acc[r]);  // V^T scatter
        }
      }
    }
    wfence();   // hb reads -> P-tail zero stores (write-after-read, same region family)
    if (tid == 0) *(u32x4*)(lds + ZO) = (u32x4){0u, 0u, 0u, 0u};
    #pragma unroll
    for (int ct = 1; ct < 4; ++ct)                       // zero P tail (causal)
      if (ct > w) *(u32x2*)(lds + prow + 16 * ct + 4 * g) = (u32x2){0u, 0u};
  }
  __syncthreads();   // the ONLY barrier: publish K and V^T (cross-wave)

  // ---------- attention: S^T = mfma(K,Q); softmax lane-local; swapped PV ----------
  unsigned at0_[8], at1_[8];   // attn output (g<2 lanes), packed bf16
  #pragma unroll
  for (int h = 0; h < 8; ++h) {
    bf16x8 bq = *(const bf16x8*)(lds + ((g == 0) ? (qrow + h * 8) : ZO));
    float sum = 0.f;
    for (int mi = 0; mi < w; ++mi) {          // full tiles below diagonal
      bf16x8 ak = *(const bf16x8*)(lds + ((g == 0) ? (OFF_K + (16 * mi + jl) * LR + h * 8) : ZO));
      f32x4 sc = MFMA16(ak, bq, zf);
      float e0 = exp2f(sc[0]), e1 = exp2f(sc[1]);   // log2e folded into Wq
      float e2 = exp2f(sc[2]), e3 = exp2f(sc[3]);
      sum += (e0 + e1) + (e2 + e3);
      *(u32x2*)(lds + prow + 16 * mi + 4 * g) = (u32x2){pk2(e0, e1), pk2(e2, e3)};
    }
    {   // diagonal tile mi == w: keep s<=q  <=>  4g+r <= jl
      bf16x8 ak = *(const bf16x8*)(lds + ((g == 0) ? (krow + h * 8) : ZO));
      f32x4 sc = MFMA16(ak, bq, zf);
      float e0 = (4 * g + 0 <= jl) ? exp2f(sc[0]) : 0.f;
      float e1 = (4 * g + 1 <= jl) ? exp2f(sc[1]) : 0.f;
      float e2 = (4 * g + 2 <= jl) ? exp2f(sc[2]) : 0.f;
      float e3 = (4 * g + 3 <= jl) ? exp2f(sc[3]) : 0.f;
      sum += (e0 + e1) + (e2 + e3);
      *(u32x2*)(lds + prow + 16 * w + 4 * g) = (u32x2){pk2(e0, e1), pk2(e2, e3)};
    }
    sum += __shfl_xor(sum, 16, 64);
    sum += __shfl_xor(sum, 32, 64);
    float inv = __builtin_amdgcn_rcpf(sum);
    wfence();   // P stores -> cross-lane bP reads
    f32x4 av = zf;   // attn^T = V^T . P^T  (K-dim = 64 tokens, full)
    #pragma unroll
    for (int ks = 0; ks < 2; ++ks) {
      bf16x8 aV = *(const bf16x8*)(lds + ((jl < 8) ? (OFF_VT + (h * 8 + jl) * LR + 32 * ks + 8 * g) : ZO));
      bf16x8 bP = *(const bf16x8*)(lds + prow + 32 * ks + 8 * g);
      av = MFMA16(aV, bP, av);
    }
    at0_[h] = pk2(av[0] * inv, av[1] * inv);   // d = 4g..4g+3 valid for g<2
    at1_[h] = pk2(av[2] * inv, av[3] * inv);
    wfence();   // bP reads -> next head's P stores (write-after-read)
  }
  // dump attn (own token row; P dead) then load proj B-frag
  if (g < 2) {
    #pragma unroll
    for (int h = 0; h < 8; ++h)
      *(u32x2*)(lds + prow + h * 8 + 4 * g) = (u32x2){at0_[h], at1_[h]};
  }
  wfence();   // attn dump -> cross-lane bat reads
  bf16x8 bat0 = *(const bf16x8*)(lds + prow + 8 * g);
  bf16x8 bat1 = *(const bf16x8*)(lds + prow + 32 + 8 * g);

  // ---------- proj (swapped) + residual: x2 stays in fp32 registers ----------
  f32x4 x2[4];
  #pragma unroll
  for (int mi = 0; mi < 4; ++mi) {
    bf16x8 a0 = *(const bf16x8*)(wsm + (24 + mi * 2 + 0) * 512 + lane * 8);
    bf16x8 a1 = *(const bf16x8*)(wsm + (24 + mi * 2 + 1) * 512 + lane * 8);
    f32x4 acc = MFMA16(a0, bat0, zf);
    acc = MFMA16(a1, bat1, acc);
    f32x4 xv = *(const f32x4*)(xb + myrow * 64 + 16 * mi + 4 * g);
    f32x4 pb = *(const f32x4*)(projb + 16 * mi + 4 * g);
    x2[mi] = xv + acc + pb;
  }

  // ---------- LN2 fully in registers (sum over g via 2 shfls) ----------
  float mean, rstd;
  {
    float s = 0.f, ss = 0.f;
    #pragma unroll
    for (int mi = 0; mi < 4; ++mi)
      #pragma unroll
      for (int r = 0; r < 4; ++r) { s += x2[mi][r]; ss += x2[mi][r] * x2[mi][r]; }
    s  += __shfl_xor(s, 16, 64);  s  += __shfl_xor(s, 32, 64);
    ss += __shfl_xor(ss, 16, 64); ss += __shfl_xor(ss, 32, 64);
    mean = s * 0.015625f;
    rstd = rsqrtf(ss * 0.015625f - mean * mean + 1e-5f);
  }
  wfence();   // bat reads -> H2 stores overwrite prow (write-after-read)
  // H2 -> own scratch row -> fc1 B-frag
  #pragma unroll
  for (int mi = 0; mi < 4; ++mi) {
    f32x4 lw = *(const f32x4*)(ln2w + 16 * mi + 4 * g);
    f32x4 lb = *(const f32x4*)(ln2b + 16 * mi + 4 * g);
    float h0 = (x2[mi][0] - mean) * rstd * lw[0] + lb[0];
    float h1 = (x2[mi][1] - mean) * rstd * lw[1] + lb[1];
    float h2 = (x2[mi][2] - mean) * rstd * lw[2] + lb[2];
    float h3 = (x2[mi][3] - mean) * rstd * lw[3] + lb[3];
    *(u32x2*)(lds + prow + 16 * mi + 4 * g) = (u32x2){pk2(h0, h1), pk2(h2, h3)};
  }
  wfence();   // H2 stores -> cross-lane hc reads
  bf16x8 hc0 = *(const bf16x8*)(lds + prow + 8 * g);
  bf16x8 hc1 = *(const bf16x8*)(lds + prow + 32 + 8 * g);
  wfence();   // hc reads -> FF1 stores overwrite prow (write-after-read)

  // ---------- FF in 4 hidden-chunks of 64 over the same scratch row ----------
  f32x4 acc2[4];
  #pragma unroll
  for (int mi = 0; mi < 4; ++mi) acc2[mi] = zf;
  #pragma unroll
  for (int c = 0; c < 4; ++c) {
    #pragma unroll
    for (int ml = 0; ml < 4; ++ml) {      // fc1 (swapped): hidden tile nt
      int nt = 4 * c + ml;
      bf16x8 a0 = *(const bf16x8*)(wsm + (32 + nt * 2 + 0) * 512 + lane * 8);
      bf16x8 a1 = *(const bf16x8*)(wsm + (32 + nt * 2 + 1) * 512 + lane * 8);
      f32x4 acc = MFMA16(a0, hc0, zf);
      acc = MFMA16(a1, hc1, acc);
      f32x4 fb1 = *(const f32x4*)(fc1b + 16 * nt + 4 * g);
      float r0 = fmaxf(acc[0] + fb1[0], 0.f), r1 = fmaxf(acc[1] + fb1[1], 0.f);
      float r2 = fmaxf(acc[2] + fb1[2], 0.f), r3 = fmaxf(acc[3] + fb1[3], 0.f);
      *(u32x2*)(lds + prow + 16 * ml + 4 * g) = (u32x2){pk2(r0, r1), pk2(r2, r3)};
    }
    wfence();   // FF1 stores -> cross-lane bf reads
    bf16x8 bf0 = *(const bf16x8*)(lds + prow + 8 * g);
    bf16x8 bf1 = *(const bf16x8*)(lds + prow + 32 + 8 * g);
    wfence();   // bf reads -> next chunk's FF1 stores (write-after-read)
    #pragma unroll
    for (int mi = 0; mi < 4; ++mi) {      // fc2 (swapped): accumulate cout tiles
      bf16x8 w20 = *(const bf16x8*)(wsm + (64 + mi * 8 + 2 * c + 0) * 512 + lane * 8);
      bf16x8 w21 = *(const bf16x8*)(wsm + (64 + mi * 8 + 2 * c + 1) * 512 + lane * 8);
      acc2[mi] = MFMA16(w20, bf0, acc2[mi]);
      acc2[mi] = MFMA16(w21, bf1, acc2[mi]);
    }
  }

  // ---------- epilogue: out = x2 + ff + fc2b, f32x4 stores from registers ----------
  {
    float* ob = out + b * 4096 + myrow * 64;
    #pragma unroll
    for (int mi = 0; mi < 4; ++mi) {
      f32x4 fb = *(const f32x4*)(fc2b + 16 * mi + 4 * g);
      f32x4 o = x2[mi] + acc2[mi] + fb;
      *(f32x4*)(ob + 16 * mi + 4 * g) = o;
    }
  }
}

extern "C" void kernel_launch(void* const* d_in, const int* in_sizes, int n_in,
                              void* d_out, int out_size, void* d_ws, size_t ws_size,
                              hipStream_t stream) {
  const float* x     = (const float*)d_in[0];
  const float* ln1w  = (const float*)d_in[1];
  const float* ln1b  = (const float*)d_in[2];
  const float* wq    = (const float*)d_in[3];
  const float* wk    = (const float*)d_in[4];
  const float* wvp   = (const float*)d_in[5];
  const float* projw = (const float*)d_in[6];
  const float* projb = (const float*)d_in[7];
  const float* ln2w  = (const float*)d_in[8];
  const float* ln2b  = (const float*)d_in[9];
  const float* fc1w  = (const float*)d_in[10];
  const float* fc1b  = (const float*)d_in[11];
  const float* fc2w  = (const float*)d_in[12];
  const float* fc2b  = (const float*)d_in[13];
  unsigned short* ws = (unsigned short*)d_ws;   // 96 KB of repacked weights
  float* out = (float*)d_out;

  prep_weights<<<dim3(96), dim3(64), 0, stream>>>(wq, wk, wvp, projw, fc1w, fc2w, ws);

  int nblk = in_sizes[0] / 4096;
  block_fused<<<dim3(nblk), dim3(256), 0, stream>>>(
      x, ln1w, ln1b, projb, ln2w, ln2b, fc1b, fc2b, ws, out);
}